// Round 12
// baseline (307.700 us; speedup 1.0000x reference)
//
#include <hip/hip_runtime.h>
#include <hip/hip_bf16.h>

#define L_SZ 1024
#define P_SZ 2048
#define HID 256
#define NH 8
#define HD 32
#define NRBF 50
#define CH 16
#define NCH 128

typedef unsigned int uint32;
typedef _Float16 half2_t __attribute__((ext_vector_type(2)));
typedef __fp16 fp16x2_t __attribute__((ext_vector_type(2)));

__constant__ float kINV_SCALE = 0.17677669529663687f; // 1/sqrt(32)

static __device__ __forceinline__ unsigned short f2h(float f) {
    union { _Float16 h; unsigned short u; } x; x.h = (_Float16)f; return x.u;
}
static __device__ __forceinline__ float h2f(unsigned short u) {
    union { unsigned short u; _Float16 h; } x; x.u = u; return (float)x.h;
}
static __device__ __forceinline__ half2_t u2h2(uint32 u) {
    union { uint32 u; half2_t h; } x; x.u = u; return x.h;
}
static __device__ __forceinline__ uint32 h22u(half2_t h) {
    union { half2_t h; uint32 u; } x; x.h = h; return x.u;
}
static __device__ __forceinline__ half2_t pk2h(float a, float b) {
    union { fp16x2_t p; half2_t h; } x; x.p = __builtin_amdgcn_cvt_pkrtz(a, b); return x.h;
}

// async global->LDS, 16B per lane. LDS dest = wave-uniform base + lane*16.
static __device__ __forceinline__ void g2l16(const void* g, void* l) {
    __builtin_amdgcn_global_load_lds(
        (__attribute__((address_space(1))) void*)(void*)g,
        (__attribute__((address_space(3))) void*)l, 16, 0, 0);
}
static __device__ __forceinline__ void g2l4(const void* g, void* l) {
    __builtin_amdgcn_global_load_lds(
        (__attribute__((address_space(1))) void*)(void*)g,
        (__attribute__((address_space(3))) void*)l, 4, 0, 0);
}

#define WAITV0 asm volatile("s_waitcnt vmcnt(0)" ::: "memory")
#define WAITV1 asm volatile("s_waitcnt vmcnt(1)" ::: "memory")
#define CFENCE asm volatile("" ::: "memory")

// ---------------------------------------------------------------------------
// Kernel 1: Q = lig@Wq+bq (f32), K = prot@Wk+bk (f16), V = prot@Wv+bv (f16)
// ---------------------------------------------------------------------------
__global__ __launch_bounds__(64) void k_proj(
    const float* __restrict__ lig, const float* __restrict__ prot,
    const float* __restrict__ Wq, const float* __restrict__ bq,
    const float* __restrict__ Wk, const float* __restrict__ bk,
    const float* __restrict__ Wv, const float* __restrict__ bv,
    float* __restrict__ Qf, unsigned short* __restrict__ Kb,
    unsigned short* __restrict__ Vb)
{
    __shared__ float As[8 * HID];
    const int t = threadIdx.x;
    const int r0 = blockIdx.x * 8;

    const float* src; const float* W; const float* bias; int mode; int row0;
    if (r0 < L_SZ)            { src = lig  + (size_t)r0 * HID;               W = Wq; bias = bq; mode = 0; row0 = r0; }
    else if (r0 < L_SZ + P_SZ){ src = prot + (size_t)(r0 - L_SZ) * HID;      W = Wk; bias = bk; mode = 1; row0 = r0 - L_SZ; }
    else                      { src = prot + (size_t)(r0 - L_SZ - P_SZ)*HID; W = Wv; bias = bv; mode = 2; row0 = r0 - L_SZ - P_SZ; }

    float4* A4 = (float4*)As;
    const float4* S4 = (const float4*)src;
    #pragma unroll
    for (int j = 0; j < 8; ++j) A4[t + j * 64] = S4[t + j * 64];
    __syncthreads();

    float acc[8][4];
    #pragma unroll
    for (int r = 0; r < 8; ++r)
        #pragma unroll
        for (int c = 0; c < 4; ++c) acc[r][c] = 0.f;

    for (int k4 = 0; k4 < 64; ++k4) {
        float4 av[8];
        #pragma unroll
        for (int r = 0; r < 8; ++r) av[r] = A4[r * 64 + k4];
        #pragma unroll
        for (int kk = 0; kk < 4; ++kk) {
            const float* wr = W + (size_t)(k4 * 4 + kk) * HID + t;
            #pragma unroll
            for (int c = 0; c < 4; ++c) {
                float wv = wr[c * 64];
                #pragma unroll
                for (int r = 0; r < 8; ++r)
                    acc[r][c] += ((const float*)&av[r])[kk] * wv;
            }
        }
    }

    #pragma unroll
    for (int c = 0; c < 4; ++c) {
        const int col = t + c * 64;
        const float bb = bias[col];
        #pragma unroll
        for (int r = 0; r < 8; ++r) {
            float v = acc[r][c] + bb;
            size_t idx = (size_t)(row0 + r) * HID + col;
            if (mode == 0)      Qf[idx] = v;
            else if (mode == 1) Kb[idx] = f2h(v);
            else                Vb[idx] = f2h(v);
        }
    }
}

// ---------------------------------------------------------------------------
// Kernel 1b: dbias = rbf @ Wrbf + brbf  ->  f16 [L*P, 8]
// 32 (l,p)-rows per 256-thread block; thread (r = t>>3, h = t&7).
// Streaming: dense g2l16 stage of 6400 B, one 50-dot per thread,
// coalesced u16 store (dbias[g0*8 + t]).
// ---------------------------------------------------------------------------
__global__ __launch_bounds__(256, 4) void k_bias(
    const float* __restrict__ rbf, const float* __restrict__ Wrbf,
    const float* __restrict__ brbf, unsigned short* __restrict__ dbias)
{
    __shared__ __align__(16) char sm[7232];          // 6400 rbf + 800 wtab + pad
    uint32* wtab = (uint32*)(sm + 6400);             // [h][j] packed half2, 25*8

    const int t = threadIdx.x;
    const int lane = t & 63;
    const int wv = t >> 6;
    const size_t g0 = (size_t)blockIdx.x * 32;       // first (l,p) row
    const char* gb = (const char*)rbf + g0 * 200;

    // stage 6400 B (proven 4-wave plan)
    g2l16(gb + wv * 1024 + (lane << 4), sm + wv * 1024);
    if (wv == 0)      g2l16(gb + 4096 + (lane << 4), sm + 4096);
    else if (wv == 1) g2l16(gb + 5120 + (lane << 4), sm + 5120);
    else if (wv == 2) g2l4 (gb + 6144 + (lane << 2), sm + 6144);

    // build packed Wrbf table: 200 entries (j 0..24, h 0..7)
    if (t < 200) {
        int j = t >> 3, h = t & 7;
        wtab[h * 25 + j] = h22u(pk2h(Wrbf[(2 * j) * NH + h], Wrbf[(2 * j + 1) * NH + h]));
    }
    const int h = t & 7;
    const int r = t >> 3;
    float b = brbf[h];

    WAITV0;
    __syncthreads();

    half2_t wrb[25];
    #pragma unroll
    for (int j = 0; j < 25; ++j) wrb[j] = u2h2(wtab[h * 25 + j]);

    const char* rrow = sm + r * 200;
    #pragma unroll
    for (int j = 0; j < 25; ++j) {
        float2 v = *(const float2*)(rrow + j * 8);
        b = __builtin_amdgcn_fdot2(pk2h(v.x, v.y), wrb[j], b, false);
    }
    dbias[g0 * 8 + t] = f2h(b);                      // contiguous u16 store
}

// ---------------------------------------------------------------------------
// Kernel 2: slim flash attn. One lig row per 256-thread block, CH=16,
// LDS = K dbuf 16K + V dbuf 16K + red = 32.8 KB -> 4 blocks/CU (16 waves).
// Half-split map: wave w -> heads {2w, 2w+1}; lane = hsub*32 + rr*2 + half.
// Thread computes half the QK dot (16 dims) + half the PV dims (O[16]);
// one shfl_xor(.,1) completes the logit. dbias read direct from global.
// Raw f16 logits stream to low half of attn_out; descending in-place
// finalize (R10-proven). Swizzled K/V staging via pre-swizzled source.
// ---------------------------------------------------------------------------
__global__ __launch_bounds__(256, 4) void k_attn(
    const float* __restrict__ Qf,
    const unsigned short* __restrict__ Kb, const unsigned short* __restrict__ Vb,
    const unsigned short* __restrict__ dbias,
    float* __restrict__ attn_out, float* __restrict__ att_ws)
{
    __shared__ __align__(16) char sm[32832];
    float* red = (float*)(sm + 32768);

    const int t = threadIdx.x;
    const int lane = t & 63;
    const int wv = t >> 6;
    const int hsub = lane >> 5;
    const int rr = (lane >> 1) & 15;      // protein row within chunk
    const int half = lane & 1;            // dim half
    const int hx = wv * 2 + hsub;         // head 0..7
    const int l = blockIdx.x;
    char* aoB = (char*)attn_out + (size_t)l * (P_SZ * NH * 4);

    // stage one 16-row K or V chunk (8 KB), swizzled source (slot^ (row&7)).
    auto stageKV = [&](const unsigned short* src, int c, char* dst) {
        const char* gb = (const char*)src + (size_t)c * (CH * 512);
        #pragma unroll
        for (int k = 0; k < 2; ++k) {
            int s = wv * 2 + k;                   // slab 0..7
            int row = s * 2 + (lane >> 5);        // 0..15
            int off = ((lane & 31) ^ (row & 7)) << 4;
            g2l16(gb + row * 512 + off, dst + s * 1024);
        }
    };

    // Q fragment: head hx, dims half*16 .. +16 (8 half2)
    half2_t qp[8];
    {
        const float* qq = Qf + (size_t)l * HID + hx * HD + half * 16;
        #pragma unroll
        for (int n = 0; n < 8; ++n) qp[n] = pk2h(qq[2 * n], qq[2 * n + 1]);
    }

    stageKV(Kb, 0, sm);
    stageKV(Vb, 0, sm + 16384);

    float mx = -3.0e38f, sme = 0.f;
    float O[16];
    #pragma unroll
    for (int d = 0; d < 16; ++d) O[d] = 0.f;

    for (int c = 0; c < NCH; ++c) {
        if (c == 0) { WAITV0; } else { WAITV1; }
        __builtin_amdgcn_s_barrier();
        CFENCE;
        const int cb = c & 1;
        const char* kb = sm + cb * 8192;
        const char* vb = sm + 16384 + cb * 8192;
        // dbias direct from global (L2-hot; compiler auto-waits before use)
        unsigned short dbu = dbias[((size_t)l * P_SZ + c * CH + rr) * 8 + hx];
        if (c + 1 < NCH) {
            stageKV(Kb, c + 1, sm + (cb ^ 1) * 8192);
            stageKV(Vb, c + 1, sm + 16384 + (cb ^ 1) * 8192);
        }
        // half QK dot (16 dims)
        float qk = 0.f;
        {
            const char* krow = kb + rr * 512;
            #pragma unroll
            for (int q = 0; q < 2; ++q) {
                int bc = hx * 64 + half * 32 + q * 16;
                uint4 kk = *(const uint4*)(krow + (((bc >> 4) ^ (rr & 7)) << 4));
                qk = __builtin_amdgcn_fdot2(u2h2(kk.x), qp[q * 4 + 0], qk, false);
                qk = __builtin_amdgcn_fdot2(u2h2(kk.y), qp[q * 4 + 1], qk, false);
                qk = __builtin_amdgcn_fdot2(u2h2(kk.z), qp[q * 4 + 2], qk, false);
                qk = __builtin_amdgcn_fdot2(u2h2(kk.w), qp[q * 4 + 3], qk, false);
            }
        }
        qk += __shfl_xor(qk, 1);                 // combine dim halves
        float lg = qk * kINV_SCALE + h2f(dbu);

        // online softmax with defer-max (THR=8)
        if (lg > mx + 8.0f) {
            float ee = __expf(mx - lg);
            sme *= ee;
            #pragma unroll
            for (int d = 0; d < 16; ++d) O[d] *= ee;
            mx = lg;
        }
        float w = __expf(lg - mx);
        sme += w;

        // half PV: O[16] += w * V[p, hx*32 + half*16 .. +16]
        {
            const char* vrow = vb + rr * 512;
            #pragma unroll
            for (int q = 0; q < 2; ++q) {
                int bc = hx * 64 + half * 32 + q * 16;
                uint4 vv = *(const uint4*)(vrow + (((bc >> 4) ^ (rr & 7)) << 4));
                half2_t x0 = u2h2(vv.x), x1 = u2h2(vv.y), x2 = u2h2(vv.z), x3 = u2h2(vv.w);
                O[q * 8 + 0] += w * (float)x0.x; O[q * 8 + 1] += w * (float)x0.y;
                O[q * 8 + 2] += w * (float)x1.x; O[q * 8 + 3] += w * (float)x1.y;
                O[q * 8 + 4] += w * (float)x2.x; O[q * 8 + 5] += w * (float)x2.y;
                O[q * 8 + 6] += w * (float)x3.x; O[q * 8 + 7] += w * (float)x3.y;
            }
        }
        // raw f16 logit (both halves store same value — benign)
        *(unsigned short*)(aoB + (c * CH + rr) * 16 + hx * 2) = f2h(lg);
    }
    WAITV0;                                      // drain raw logit stores

    // ---- merge (m,s) over the 32-lane head group (halves duplicated) ----
    float mg = mx;
    #pragma unroll
    for (int msk = 1; msk <= 16; msk <<= 1) mg = fmaxf(mg, __shfl_xor(mg, msk));
    float e = __expf(mx - mg);
    sme *= e;
    #pragma unroll
    for (int msk = 1; msk <= 16; msk <<= 1) sme += __shfl_xor(sme, msk);
    const float invt = 2.0f / sme;               // halves double-counted

    // ---- O: rescale then reduce over rr-lanes (masks 2..16 keep dim-half) --
    #pragma unroll
    for (int d = 0; d < 16; ++d) O[d] *= e;
    #pragma unroll
    for (int msk = 2; msk <= 16; msk <<= 1) {
        #pragma unroll
        for (int d = 0; d < 16; ++d) O[d] += __shfl_xor(O[d], msk);
    }
    if (rr == 0) {
        float* dst = att_ws + (size_t)l * HID + hx * HD + half * 16;
        #pragma unroll
        for (int n = 0; n < 4; ++n)
            *(float4*)(dst + n * 4) = make_float4(O[n*4+0]*invt, O[n*4+1]*invt,
                                                  O[n*4+2]*invt, O[n*4+3]*invt);
        if (half == 0) { red[hx * 2] = mg; red[hx * 2 + 1] = invt; }
    }
    __syncthreads();

    // ---- in-place finalize raw f16 -> f32 weights (descending, proven) ----
    {
        const int hA = 2 * (t & 3);
        const float mA = red[hA * 2],     iA = red[hA * 2 + 1];
        const float mB = red[hA * 2 + 2], iB = red[hA * 2 + 3];
        for (int n = 31; n >= 0; --n) {
            int j = t + n * 256;
            uint32 a = *(const uint32*)(aoB + 4 * j);
            float w0 = __expf(h2f((unsigned short)(a & 0xffffu)) - mA) * iA;
            float w1 = __expf(h2f((unsigned short)(a >> 16))     - mB) * iB;
            __syncthreads();
            *(float2*)(aoB + 8 * (size_t)j) = make_float2(w0, w1);
        }
    }
}

// ---------------------------------------------------------------------------
// Kernel 3: y = lig + attended@Wo + bo; LayerNorm
// ---------------------------------------------------------------------------
__global__ __launch_bounds__(256) void k_out(
    const float* __restrict__ att, const float* __restrict__ lig,
    const float* __restrict__ Wo, const float* __restrict__ bo,
    const float* __restrict__ gamma, const float* __restrict__ beta,
    float* __restrict__ out)
{
    __shared__ float a[HID];
    __shared__ float red[8];
    const int l = blockIdx.x, t = threadIdx.x;
    if (t < 64) ((float4*)a)[t] = ((const float4*)(att + (size_t)l * HID))[t];
    __syncthreads();

    float acc = bo[t];
    for (int k4 = 0; k4 < 64; ++k4) {
        float4 av = ((float4*)a)[k4];
        const float* wr = Wo + (size_t)(k4 * 4) * HID + t;
        acc += av.x * wr[0];
        acc += av.y * wr[HID];
        acc += av.z * wr[2 * HID];
        acc += av.w * wr[3 * HID];
    }
    float y = lig[(size_t)l * HID + t] + acc;

    float s = y, sq = y * y;
    #pragma unroll
    for (int msk = 1; msk < 64; msk <<= 1) {
        s  += __shfl_xor(s, msk);
        sq += __shfl_xor(sq, msk);
    }
    const int lane = t & 63, wvi = t >> 6;
    if (lane == 0) { red[wvi * 2] = s; red[wvi * 2 + 1] = sq; }
    __syncthreads();
    float ts = red[0] + red[2] + red[4] + red[6];
    float tq = red[1] + red[3] + red[5] + red[7];
    float mu = ts * (1.0f / HID);
    float var = tq * (1.0f / HID) - mu * mu;
    out[(size_t)l * HID + t] = (y - mu) * rsqrtf(var + 1e-5f) * gamma[t] + beta[t];
}

// ---------------------------------------------------------------------------
extern "C" void kernel_launch(void* const* d_in, const int* in_sizes, int n_in,
                              void* d_out, int out_size, void* d_ws, size_t ws_size,
                              hipStream_t stream)
{
    (void)in_sizes; (void)n_in; (void)out_size; (void)ws_size;

    const float* lig   = (const float*)d_in[0];
    const float* prot  = (const float*)d_in[1];
    const float* rbf   = (const float*)d_in[2];
    const float* Wq    = (const float*)d_in[5];
    const float* bq    = (const float*)d_in[6];
    const float* Wk    = (const float*)d_in[7];
    const float* bk    = (const float*)d_in[8];
    const float* Wv    = (const float*)d_in[9];
    const float* bv    = (const float*)d_in[10];
    const float* Wrbf  = (const float*)d_in[11];
    const float* brbf  = (const float*)d_in[12];
    const float* Wo    = (const float*)d_in[13];
    const float* bo    = (const float*)d_in[14];
    const float* gamma = (const float*)d_in[15];
    const float* beta  = (const float*)d_in[16];

    float* out0 = (float*)d_out;                          // [1024,256]
    float* attn = (float*)d_out + (size_t)L_SZ * HID;     // [1024,2048,8]

    char* ws = (char*)d_ws;
    float*          Qf     = (float*)ws;                          // 1 MB
    unsigned short* Kb     = (unsigned short*)(ws + (1u << 20));  // 1 MB
    unsigned short* Vb     = (unsigned short*)(ws + (2u << 20));  // 1 MB
    float*          att_ws = (float*)(ws + (3u << 20));           // 1 MB
    unsigned short* dbias  = (unsigned short*)(ws + (4u << 20));  // 32 MB

    hipLaunchKernelGGL(k_proj, dim3((L_SZ + 2 * P_SZ) / 8), dim3(64), 0, stream,
                       lig, prot, Wq, bq, Wk, bk, Wv, bv, Qf, Kb, Vb);
    hipLaunchKernelGGL(k_bias, dim3((L_SZ * P_SZ) / 32), dim3(256), 0, stream,
                       rbf, Wrbf, brbf, dbias);
    hipLaunchKernelGGL(k_attn, dim3(L_SZ), dim3(256), 0, stream,
                       Qf, Kb, Vb, dbias, attn, att_ws);
    hipLaunchKernelGGL(k_out, dim3(L_SZ), dim3(256), 0, stream,
                       att_ws, lig, Wo, bo, gamma, beta, out0);
}